// Round 12
// baseline (1025.430 us; speedup 1.0000x reference)
//
#include <hip/hip_runtime.h>

typedef __bf16 bf16_t;
typedef __bf16 bf16x8 __attribute__((ext_vector_type(8)));
typedef __bf16 bf16x4 __attribute__((ext_vector_type(4)));
typedef float  f32x4  __attribute__((ext_vector_type(4)));

#define T_TOK 8192
#define DIM   1024
#define DFF   4096
#define NEXP  8

__device__ __forceinline__ void gll16(const void* g, void* l) {
    __builtin_amdgcn_global_load_lds(
        (const __attribute__((address_space(1))) char*)g,
        (__attribute__((address_space(3))) char*)l, 16, 0, 0);
}

// ---------------- transpose + convert: src [R][C] f32 -> dst [C][R] bf16, per expert ----------------
__global__ __launch_bounds__(256) void transpose_cvt_kernel(
    const float* __restrict__ src, bf16_t* __restrict__ dst, int R, int C) {
    __shared__ float t[64][65];
    int e = blockIdx.z;
    src += (size_t)e * R * C;
    dst += (size_t)e * R * C;
    int r0 = blockIdx.y * 64, c0 = blockIdx.x * 64;
    int tid = threadIdx.x;
    {
        int cg = tid & 15, r = tid >> 4;
#pragma unroll
        for (int i = 0; i < 4; ++i) {
            int rr = r + i * 16;
            float4 v = *(const float4*)&src[(size_t)(r0 + rr) * C + c0 + cg * 4];
            t[rr][cg * 4 + 0] = v.x; t[rr][cg * 4 + 1] = v.y;
            t[rr][cg * 4 + 2] = v.z; t[rr][cg * 4 + 3] = v.w;
        }
    }
    __syncthreads();
    {
        int rr = tid & 7, c = tid >> 3;
#pragma unroll
        for (int i = 0; i < 2; ++i) {
            int cc = c + i * 32;
            bf16x8 o;
#pragma unroll
            for (int j = 0; j < 8; ++j) o[j] = (bf16_t)t[rr * 8 + j][cc];
            *(bf16x8*)&dst[(size_t)(c0 + cc) * R + r0 + rr * 8] = o;
        }
    }
}

// ---------------- router: wave per token, f64 accumulation ----------------
__global__ __launch_bounds__(256) void router_kernel(
    const float* __restrict__ x, const float* __restrict__ noise,
    const float* __restrict__ w_route, const float* __restrict__ b_route,
    const float* __restrict__ w_noise, const float* __restrict__ b_noise,
    int* __restrict__ counts, int* __restrict__ lists, float* __restrict__ gate_tok)
{
    int wave = threadIdx.x >> 6;
    int lane = threadIdx.x & 63;
    int t = blockIdx.x * 4 + wave;
    if (t >= T_TOK) return;

    const float* xr = x + (size_t)t * DIM;
    double aR[NEXP], aN[NEXP];
#pragma unroll
    for (int e = 0; e < NEXP; ++e) { aR[e] = 0.0; aN[e] = 0.0; }

#pragma unroll 4
    for (int i = 0; i < 16; ++i) {
        int k = lane + i * 64;
        double xv = (double)xr[k];
        const float4* wr4 = (const float4*)(w_route + (size_t)k * 8);
        const float4* wn4 = (const float4*)(w_noise + (size_t)k * 8);
        float4 r0 = wr4[0], r1 = wr4[1];
        float4 n0 = wn4[0], n1 = wn4[1];
        aR[0] += xv * (double)r0.x; aR[1] += xv * (double)r0.y;
        aR[2] += xv * (double)r0.z; aR[3] += xv * (double)r0.w;
        aR[4] += xv * (double)r1.x; aR[5] += xv * (double)r1.y;
        aR[6] += xv * (double)r1.z; aR[7] += xv * (double)r1.w;
        aN[0] += xv * (double)n0.x; aN[1] += xv * (double)n0.y;
        aN[2] += xv * (double)n0.z; aN[3] += xv * (double)n0.w;
        aN[4] += xv * (double)n1.x; aN[5] += xv * (double)n1.y;
        aN[6] += xv * (double)n1.z; aN[7] += xv * (double)n1.w;
    }
#pragma unroll
    for (int e = 0; e < NEXP; ++e) {
        for (int s = 1; s < 64; s <<= 1) {
            aR[e] += __shfl_xor(aR[e], s);
            aN[e] += __shfl_xor(aN[e], s);
        }
    }
    if (lane == 0) {
        double nv[NEXP];
#pragma unroll
        for (int e = 0; e < NEXP; ++e) {
            double lg = aR[e] + (double)b_route[e];
            double nl = aN[e] + (double)b_noise[e];
            double sp = (nl > 30.0) ? nl : log1p(exp(nl));
            nv[e] = lg + (double)noise[(size_t)t * 8 + e] * sp;
        }
        int i1 = 0;
#pragma unroll
        for (int e = 1; e < NEXP; ++e) if (nv[e] > nv[i1]) i1 = e;
        int i2 = (i1 == 0) ? 1 : 0;
#pragma unroll
        for (int e = 0; e < NEXP; ++e) if (e != i1 && nv[e] > nv[i2]) i2 = e;
        double m = nv[i1];
        double e2 = exp(nv[i2] - m);
        double s = 1.0 + e2;
        gate_tok[2 * t + 0] = (float)(1.0 / s);
        gate_tok[2 * t + 1] = (float)(e2 / s);
        int p1 = atomicAdd(&counts[i1], 1);
        lists[i1 * T_TOK + p1] = 2 * t + 0;
        int p2 = atomicAdd(&counts[i2], 1);
        lists[i2 * T_TOK + p2] = 2 * t + 1;
    }
}

// ---------------- prefix: bases[e] = exclusive prefix sum of counts ----------------
__global__ void prefix_kernel(const int* __restrict__ counts, int* __restrict__ bases) {
    if (threadIdx.x == 0 && blockIdx.x == 0) {
        int s = 0;
#pragma unroll
        for (int e = 0; e < NEXP; ++e) { bases[e] = s; s += counts[e]; }
    }
}

// ---------------- pack A: flat over the 16384 packed rows ----------------
__global__ __launch_bounds__(256) void pack_a_kernel(
    const float* __restrict__ x, const int* __restrict__ bases,
    const int* __restrict__ lists, bf16_t* __restrict__ Ap, int* __restrict__ inv)
{
    int wave = threadIdx.x >> 6, lane = threadIdx.x & 63;
    int p = blockIdx.x * 4 + wave;
    int e = 0;
#pragma unroll
    for (int i = 1; i < NEXP; ++i) e += (p >= bases[i]);
    int pos = p - bases[e];
    int entry = lists[e * T_TOK + pos];
    if (lane == 0) inv[entry] = p;
    const float4* src = (const float4*)(x + (size_t)(entry >> 1) * DIM);
    bf16x4* dst = (bf16x4*)(Ap + (size_t)p * DIM);
#pragma unroll
    for (int j = 0; j < 4; ++j) {
        float4 v = src[lane + j * 64];
        bf16x4 o;
        o[0] = (bf16_t)v.x; o[1] = (bf16_t)v.y; o[2] = (bf16_t)v.z; o[3] = (bf16_t)v.w;
        dst[lane + j * 64] = o;
    }
}

// ---------------- grouped GEMM: 256x128 tile, BK=32, 4 waves (2m x 2n), counted-vmcnt dbuf ----------------
// LDS-traffic round: per-wave output 128x64 (acc[8][4]) cuts LDS reads to
// 12 b128 per K-tile/wave (0.0229 B/FLOP vs 0.0305 at 64x64/wave). LDS =
// (A 16KB + B 8KB) x 2 dbuf = 48KB -> 3 blocks/CU.
// BK=32 swizzle (rows are 64B = 4x16B slots): slot' = slot ^ ((row>>1)&3).
//   write: linear gll16 dest; global col pre-swizzle kcs, since within each
//          1KB chunk row = c*16+(lane>>2) -> (row>>1)&3 = (lane>>3)&3.
//   read:  sw = (g ^ ((ln15>>1)&3))<<3, g = lane>>4. Banks (4r+s')%8 hit
//          2-way only (free, m136).
// XCD expert-clustering (r9/r10-proven): e = wg&7. Counted s_waitcnt vmcnt(6)
// (one STAGE = 6 gll16/thread: A 4 + B 2). Raw s_barrier. T5 setprio.
// MODE 0: H[base+row] = relu(Ap[base+row] @ w1t^T + b1), K=1024, N=4096
// MODE 1: Yp[base+row] = gate * (H[base+row] @ w2t^T + b2), K=4096, N=1024
template<int K, int MODE>
__global__ __launch_bounds__(256) void moe_gemm_kernel(
    const bf16_t* __restrict__ Asrc, const bf16_t* __restrict__ Wt,
    const float* __restrict__ bias,
    const int* __restrict__ counts, const int* __restrict__ bases,
    const int* __restrict__ lists, const float* __restrict__ gate_tok,
    bf16_t* __restrict__ Hout, float* __restrict__ Yp)
{
    constexpr int N = (MODE == 0) ? DFF : DIM;
    constexpr int NT = K / 32;   // 32 or 128, always even
    constexpr int NY = N / 128;  // 32 or 8

    int wg = blockIdx.x + 32 * (blockIdx.y + NY * blockIdx.z);
    int e = wg & 7;
    int inner = wg >> 3;
    int xi = inner & 31;
    int yi = inner >> 5;

    int cnt = counts[e];
    int m0 = xi * 256;
    if (m0 >= cnt) return;
    int base = bases[e];
    int n0 = yi * 128;
    const int* list = lists + e * T_TOK;
    const bf16_t* W = Wt + (size_t)e * N * K;

    __shared__ __attribute__((aligned(16))) bf16_t Ah0[256 * 32];
    __shared__ __attribute__((aligned(16))) bf16_t Bh0[128 * 32];
    __shared__ __attribute__((aligned(16))) bf16_t Ah1[256 * 32];
    __shared__ __attribute__((aligned(16))) bf16_t Bh1[128 * 32];

    int tid = threadIdx.x;
    int lane = tid & 63;
    int wave = tid >> 6;               // 0..3
    int wr = wave >> 1, wc = wave & 1; // 2m x 2n

    // staging: chunk = 1KB = 16 rows x 64B; lane -> row c*16+(lane>>2), slot lane&3
    // global k pre-swizzle so LDS-linear holds slot^( (row>>1)&3 )
    int kcs = (((lane & 3) ^ ((lane >> 3) & 3)) << 3);   // bf16 col offset
    const bf16_t* pA[4];
    const bf16_t* pB[2];
#pragma unroll
    for (int i = 0; i < 4; ++i) {
        int c = wave * 4 + i;            // A chunk 0..15
        int r = c * 16 + (lane >> 2);    // row in 256-row tile
        int ridx = m0 + r; if (ridx > cnt - 1) ridx = cnt - 1;
        pA[i] = Asrc + (size_t)(base + ridx) * K + kcs;
    }
#pragma unroll
    for (int i = 0; i < 2; ++i) {
        int c = wave * 2 + i;            // B chunk 0..7
        int r = c * 16 + (lane >> 2);    // row in 128-row tile
        pB[i] = W + (size_t)(n0 + r) * K + kcs;
    }

    f32x4 acc[8][4];
#pragma unroll
    for (int m = 0; m < 8; ++m)
#pragma unroll
        for (int n = 0; n < 4; ++n)
            acc[m][n] = (f32x4){0.f, 0.f, 0.f, 0.f};

    int g = lane >> 4, ln15 = lane & 15;
    int sw = ((g ^ ((ln15 >> 1) & 3)) << 3);   // swizzled 16B slot (bf16 offset)

#define STAGE(An, Bn, k0) do {                                               \
    _Pragma("unroll") for (int i = 0; i < 4; ++i)                            \
        gll16(pA[i] + (k0), (An) + (wave * 4 + i) * 512);                    \
    _Pragma("unroll") for (int i = 0; i < 2; ++i)                            \
        gll16(pB[i] + (k0), (Bn) + (wave * 2 + i) * 512);                    \
    } while (0)

#define COMPUTE(Ab, Bb) do {                                                 \
    bf16x8 b[4];                                                             \
    _Pragma("unroll") for (int n = 0; n < 4; ++n)                            \
        b[n] = *(const bf16x8*)((Bb) + (wc * 64 + n * 16 + ln15) * 32 + sw); \
    __builtin_amdgcn_s_setprio(1);                                           \
    _Pragma("unroll") for (int m = 0; m < 8; ++m) {                          \
        bf16x8 a = *(const bf16x8*)((Ab) + (wr * 128 + m * 16 + ln15) * 32 + sw); \
        _Pragma("unroll") for (int n = 0; n < 4; ++n)                        \
            acc[m][n] = __builtin_amdgcn_mfma_f32_16x16x32_bf16(a, b[n], acc[m][n], 0, 0, 0); \
    }                                                                        \
    __builtin_amdgcn_s_setprio(0);                                           \
    } while (0)

#define FENCE() __builtin_amdgcn_sched_barrier(0)
#define WAITV(n) asm volatile("s_waitcnt vmcnt(" #n ")" ::: "memory")

    STAGE(Ah0, Bh0, 0);                     // outstanding: 6

    for (int kt = 0; kt < NT; kt += 2) {
        if (kt + 1 < NT) { STAGE(Ah1, Bh1, (kt + 1) * 32); WAITV(6); }
        else             { WAITV(0); }
        FENCE(); __builtin_amdgcn_s_barrier(); FENCE();
        COMPUTE(Ah0, Bh0);
        FENCE(); __builtin_amdgcn_s_barrier(); FENCE();
        if (kt + 2 < NT) { STAGE(Ah0, Bh0, (kt + 2) * 32); WAITV(6); }
        else             { WAITV(0); }
        FENCE(); __builtin_amdgcn_s_barrier(); FENCE();
        COMPUTE(Ah1, Bh1);
        FENCE(); __builtin_amdgcn_s_barrier(); FENCE();
    }
#undef STAGE
#undef COMPUTE
#undef FENCE
#undef WAITV

    // epilogue
    int l4 = lane >> 4;
    float bs[4];
#pragma unroll
    for (int n = 0; n < 4; ++n)
        bs[n] = bias[e * N + n0 + wc * 64 + n * 16 + ln15];
#pragma unroll
    for (int m = 0; m < 8; ++m) {
#pragma unroll
        for (int j = 0; j < 4; ++j) {
            int grow = m0 + wr * 128 + m * 16 + l4 * 4 + j;
            if (grow >= cnt) continue;
            if constexpr (MODE == 0) {
#pragma unroll
                for (int n = 0; n < 4; ++n) {
                    int gcol = n0 + wc * 64 + n * 16 + ln15;
                    float v = acc[m][n][j] + bs[n];
                    Hout[(size_t)(base + grow) * DFF + gcol] = (bf16_t)fmaxf(v, 0.f);
                }
            } else {
                float gt = gate_tok[list[grow]];
#pragma unroll
                for (int n = 0; n < 4; ++n) {
                    int gcol = n0 + wc * 64 + n * 16 + ln15;
                    Yp[(size_t)(base + grow) * DIM + gcol] = gt * (acc[m][n][j] + bs[n]);
                }
            }
        }
    }
}

// ---------------- combine: out[t] = Yp[inv[2t]] + Yp[inv[2t+1]], 2 rows/block ----------------
__global__ __launch_bounds__(256) void combine_kernel(
    const float* __restrict__ Yp, const int* __restrict__ inv,
    float* __restrict__ out)
{
#pragma unroll
    for (int q = 0; q < 2; ++q) {
        int t = blockIdx.x * 2 + q;
        int p0 = inv[2 * t], p1 = inv[2 * t + 1];
        const float4* a = (const float4*)(Yp + (size_t)p0 * DIM);
        const float4* b = (const float4*)(Yp + (size_t)p1 * DIM);
        float4* o = (float4*)(out + (size_t)t * DIM);
        int i = threadIdx.x;
        float4 va = a[i], vb = b[i];
        o[i] = make_float4(va.x + vb.x, va.y + vb.y, va.z + vb.z, va.w + vb.w);
    }
}

extern "C" void kernel_launch(void* const* d_in, const int* in_sizes, int n_in,
                              void* d_out, int out_size, void* d_ws, size_t ws_size,
                              hipStream_t stream) {
    const float* x       = (const float*)d_in[0];
    const float* noise   = (const float*)d_in[1];
    const float* w_route = (const float*)d_in[2];
    const float* b_route = (const float*)d_in[3];
    const float* w_noise = (const float*)d_in[4];
    const float* b_noise = (const float*)d_in[5];
    const float* w1      = (const float*)d_in[6];
    const float* b1      = (const float*)d_in[7];
    const float* w2      = (const float*)d_in[8];
    const float* b2      = (const float*)d_in[9];
    float* out = (float*)d_out;

    char* ws = (char*)d_ws;
    size_t off = 0;
    auto alloc = [&](size_t bytes) {
        off = (off + 255) & ~(size_t)255;
        size_t r = off; off += bytes; return r;
    };
    int*    counts   = (int*)   (ws + alloc(32));
    int*    bases    = (int*)   (ws + alloc(32));
    int*    lists    = (int*)   (ws + alloc((size_t)NEXP * T_TOK * 4));
    float*  gate_tok = (float*) (ws + alloc((size_t)T_TOK * 2 * 4));
    int*    inv      = (int*)   (ws + alloc((size_t)T_TOK * 2 * 4));
    bf16_t* w1t      = (bf16_t*)(ws + alloc((size_t)NEXP * DFF * DIM * 2));
    bf16_t* w2t      = (bf16_t*)(ws + alloc((size_t)NEXP * DIM * DFF * 2));
    bf16_t* Ap       = (bf16_t*)(ws + alloc((size_t)T_TOK * 2 * DIM * 2));
    bf16_t* H        = (bf16_t*)(ws + alloc((size_t)T_TOK * 2 * DFF * 2));
    float*  Yp       = (float*)w1t;   // w1t dead after GEMM1
    (void)ws_size; (void)in_sizes; (void)n_in; (void)out_size;

    hipMemsetAsync(counts, 0, 32, stream);

    transpose_cvt_kernel<<<dim3(DFF / 64, DIM / 64, NEXP), 256, 0, stream>>>(w1, w1t, DIM, DFF);
    transpose_cvt_kernel<<<dim3(DIM / 64, DFF / 64, NEXP), 256, 0, stream>>>(w2, w2t, DFF, DIM);

    router_kernel<<<T_TOK / 4, 256, 0, stream>>>(x, noise, w_route, b_route, w_noise, b_noise,
                                                 counts, lists, gate_tok);
    prefix_kernel<<<1, 64, 0, stream>>>(counts, bases);
    pack_a_kernel<<<T_TOK * 2 / 4, 256, 0, stream>>>(x, bases, lists, Ap, inv);

    moe_gemm_kernel<DIM, 0><<<dim3(32, DFF / 128, NEXP), 256, 0, stream>>>(
        Ap, w1t, b1, counts, bases, lists, gate_tok, H, nullptr);
    moe_gemm_kernel<DFF, 1><<<dim3(32, DIM / 128, NEXP), 256, 0, stream>>>(
        H, w2t, b2, counts, bases, lists, gate_tok, nullptr, Yp);

    combine_kernel<<<T_TOK / 2, 256, 0, stream>>>(Yp, inv, out);
}

// Round 13
// 816.681 us; speedup vs baseline: 1.2556x; 1.2556x over previous
//
#include <hip/hip_runtime.h>

typedef __bf16 bf16_t;
typedef __bf16 bf16x8 __attribute__((ext_vector_type(8)));
typedef __bf16 bf16x4 __attribute__((ext_vector_type(4)));
typedef float  f32x4  __attribute__((ext_vector_type(4)));

#define T_TOK 8192
#define DIM   1024
#define DFF   4096
#define NEXP  8

__device__ __forceinline__ void gll16(const void* g, void* l) {
    __builtin_amdgcn_global_load_lds(
        (const __attribute__((address_space(1))) char*)g,
        (__attribute__((address_space(3))) char*)l, 16, 0, 0);
}

// ---------------- transpose + convert: src [R][C] f32 -> dst [C][R] bf16, per expert ----------------
__global__ __launch_bounds__(256) void transpose_cvt_kernel(
    const float* __restrict__ src, bf16_t* __restrict__ dst, int R, int C) {
    __shared__ float t[64][65];
    int e = blockIdx.z;
    src += (size_t)e * R * C;
    dst += (size_t)e * R * C;
    int r0 = blockIdx.y * 64, c0 = blockIdx.x * 64;
    int tid = threadIdx.x;
    {
        int cg = tid & 15, r = tid >> 4;
#pragma unroll
        for (int i = 0; i < 4; ++i) {
            int rr = r + i * 16;
            float4 v = *(const float4*)&src[(size_t)(r0 + rr) * C + c0 + cg * 4];
            t[rr][cg * 4 + 0] = v.x; t[rr][cg * 4 + 1] = v.y;
            t[rr][cg * 4 + 2] = v.z; t[rr][cg * 4 + 3] = v.w;
        }
    }
    __syncthreads();
    {
        int rr = tid & 7, c = tid >> 3;
#pragma unroll
        for (int i = 0; i < 2; ++i) {
            int cc = c + i * 32;
            bf16x8 o;
#pragma unroll
            for (int j = 0; j < 8; ++j) o[j] = (bf16_t)t[rr * 8 + j][cc];
            *(bf16x8*)&dst[(size_t)(c0 + cc) * R + r0 + rr * 8] = o;
        }
    }
}

// ---------------- router: wave per token, f64 accumulation ----------------
__global__ __launch_bounds__(256) void router_kernel(
    const float* __restrict__ x, const float* __restrict__ noise,
    const float* __restrict__ w_route, const float* __restrict__ b_route,
    const float* __restrict__ w_noise, const float* __restrict__ b_noise,
    int* __restrict__ counts, int* __restrict__ lists, float* __restrict__ gate_tok)
{
    int wave = threadIdx.x >> 6;
    int lane = threadIdx.x & 63;
    int t = blockIdx.x * 4 + wave;
    if (t >= T_TOK) return;

    const float* xr = x + (size_t)t * DIM;
    double aR[NEXP], aN[NEXP];
#pragma unroll
    for (int e = 0; e < NEXP; ++e) { aR[e] = 0.0; aN[e] = 0.0; }

#pragma unroll 4
    for (int i = 0; i < 16; ++i) {
        int k = lane + i * 64;
        double xv = (double)xr[k];
        const float4* wr4 = (const float4*)(w_route + (size_t)k * 8);
        const float4* wn4 = (const float4*)(w_noise + (size_t)k * 8);
        float4 r0 = wr4[0], r1 = wr4[1];
        float4 n0 = wn4[0], n1 = wn4[1];
        aR[0] += xv * (double)r0.x; aR[1] += xv * (double)r0.y;
        aR[2] += xv * (double)r0.z; aR[3] += xv * (double)r0.w;
        aR[4] += xv * (double)r1.x; aR[5] += xv * (double)r1.y;
        aR[6] += xv * (double)r1.z; aR[7] += xv * (double)r1.w;
        aN[0] += xv * (double)n0.x; aN[1] += xv * (double)n0.y;
        aN[2] += xv * (double)n0.z; aN[3] += xv * (double)n0.w;
        aN[4] += xv * (double)n1.x; aN[5] += xv * (double)n1.y;
        aN[6] += xv * (double)n1.z; aN[7] += xv * (double)n1.w;
    }
#pragma unroll
    for (int e = 0; e < NEXP; ++e) {
        for (int s = 1; s < 64; s <<= 1) {
            aR[e] += __shfl_xor(aR[e], s);
            aN[e] += __shfl_xor(aN[e], s);
        }
    }
    if (lane == 0) {
        double nv[NEXP];
#pragma unroll
        for (int e = 0; e < NEXP; ++e) {
            double lg = aR[e] + (double)b_route[e];
            double nl = aN[e] + (double)b_noise[e];
            double sp = (nl > 30.0) ? nl : log1p(exp(nl));
            nv[e] = lg + (double)noise[(size_t)t * 8 + e] * sp;
        }
        int i1 = 0;
#pragma unroll
        for (int e = 1; e < NEXP; ++e) if (nv[e] > nv[i1]) i1 = e;
        int i2 = (i1 == 0) ? 1 : 0;
#pragma unroll
        for (int e = 0; e < NEXP; ++e) if (e != i1 && nv[e] > nv[i2]) i2 = e;
        double m = nv[i1];
        double e2 = exp(nv[i2] - m);
        double s = 1.0 + e2;
        gate_tok[2 * t + 0] = (float)(1.0 / s);
        gate_tok[2 * t + 1] = (float)(e2 / s);
        int p1 = atomicAdd(&counts[i1], 1);
        lists[i1 * T_TOK + p1] = 2 * t + 0;
        int p2 = atomicAdd(&counts[i2], 1);
        lists[i2 * T_TOK + p2] = 2 * t + 1;
    }
}

// ---------------- pack A: flat over 16384 packed rows; bases derived from counts inline ----------------
__global__ __launch_bounds__(256) void pack_a_kernel(
    const float* __restrict__ x, const int* __restrict__ counts,
    const int* __restrict__ lists, bf16_t* __restrict__ Ap, int* __restrict__ inv)
{
    int wave = threadIdx.x >> 6, lane = threadIdx.x & 63;
    int p = blockIdx.x * 4 + wave;
    int bs[NEXP];
    {
        int s = 0;
#pragma unroll
        for (int i = 0; i < NEXP; ++i) { bs[i] = s; s += counts[i]; }
    }
    int e = 0;
#pragma unroll
    for (int i = 1; i < NEXP; ++i) e += (p >= bs[i]);
    int pos = p - bs[e];
    int entry = lists[e * T_TOK + pos];
    if (lane == 0) inv[entry] = p;
    const float4* src = (const float4*)(x + (size_t)(entry >> 1) * DIM);
    bf16x4* dst = (bf16x4*)(Ap + (size_t)p * DIM);
#pragma unroll
    for (int j = 0; j < 4; ++j) {
        float4 v = src[lane + j * 64];
        bf16x4 o;
        o[0] = (bf16_t)v.x; o[1] = (bf16_t)v.y; o[2] = (bf16_t)v.z; o[3] = (bf16_t)v.w;
        dst[lane + j * 64] = o;
    }
}

// ---------------- grouped GEMM: 128x128 tile, BK=64, 4 waves, single-barrier dbuf ----------------
// r10-proven geometry (239us/GEMM) + the catalog minimum-2-phase loop:
//   STAGE(next tile, buf^1) -> COMPUTE(cur buf) -> s_waitcnt vmcnt(0) -> s_barrier
// ONE barrier per K-tile (r10 had two). Drain sits AFTER compute: next tile's
// loads get the full compute phase (~1250 cyc) to land, so the drain is cheap.
// Safety: buf^1 writes issue after the previous barrier (its readers done);
// drain+barrier => buf^1 fully landed & visible before any wave reads it.
// XCD expert-clustering (e = wg&7, r9/r10-proven: FETCH 295->137MB).
// T2 swizzle both-sides (0 conflicts since r2). T5 setprio around MFMA.
// bases derived inline from counts (prefix kernel eliminated).
// MODE 0: H[base+row] = relu(Ap[base+row] @ w1t^T + b1), K=1024, N=4096
// MODE 1: Yp[base+row] = gate * (H[base+row] @ w2t^T + b2), K=4096, N=1024
template<int K, int MODE>
__global__ __launch_bounds__(256) void moe_gemm_kernel(
    const bf16_t* __restrict__ Asrc, const bf16_t* __restrict__ Wt,
    const float* __restrict__ bias,
    const int* __restrict__ counts, const int* __restrict__ lists,
    const float* __restrict__ gate_tok,
    bf16_t* __restrict__ Hout, float* __restrict__ Yp)
{
    constexpr int N = (MODE == 0) ? DFF : DIM;
    constexpr int NT = K / 64;   // 16 or 64, always even
    constexpr int NY = N / 128;  // 32 or 8

    int wg = blockIdx.x + 64 * (blockIdx.y + NY * blockIdx.z);
    int e = wg & 7;
    int inner = wg >> 3;
    int xi = inner & 63;
    int yi = inner >> 6;

    int cnt, base;
    {
        int s = 0, c = 0;
#pragma unroll
        for (int i = 0; i < NEXP; ++i) {
            int ci = counts[i];
            if (i == e) { base = s; c = ci; }
            s += ci;
        }
        cnt = c;
    }
    int m0 = xi * 128;
    if (m0 >= cnt) return;
    int n0 = yi * 128;
    const int* list = lists + e * T_TOK;
    const bf16_t* W = Wt + (size_t)e * N * K;

    __shared__ __attribute__((aligned(16))) bf16_t Ah0[128 * 64];
    __shared__ __attribute__((aligned(16))) bf16_t Bh0[128 * 64];
    __shared__ __attribute__((aligned(16))) bf16_t Ah1[128 * 64];
    __shared__ __attribute__((aligned(16))) bf16_t Bh1[128 * 64];

    int tid = threadIdx.x;
    int lane = tid & 63;
    int wave = tid >> 6;
    int wr = wave >> 1, wc = wave & 1;

    int kcs = (((lane & 7) ^ (lane >> 3)) << 3);
    const bf16_t* pA[4];
    const bf16_t* pB[4];
#pragma unroll
    for (int i = 0; i < 4; ++i) {
        int c = wave * 4 + i;
        int r = c * 8 + (lane >> 3);
        int ridx = m0 + r; if (ridx > cnt - 1) ridx = cnt - 1;
        pA[i] = Asrc + (size_t)(base + ridx) * K + kcs;
        pB[i] = W + (size_t)(n0 + r) * K + kcs;
    }

    f32x4 acc[4][4];
#pragma unroll
    for (int m = 0; m < 4; ++m)
#pragma unroll
        for (int n = 0; n < 4; ++n)
            acc[m][n] = (f32x4){0.f, 0.f, 0.f, 0.f};

    int g = lane >> 4, ln15 = lane & 15, ln7 = lane & 7;

#define STAGE(An, Bn, k0) do {                                               \
    _Pragma("unroll") for (int i = 0; i < 4; ++i) {                          \
        int c = wave * 4 + i;                                                \
        gll16(pA[i] + (k0), (An) + c * 512);                                 \
        gll16(pB[i] + (k0), (Bn) + c * 512);                                 \
    } } while (0)

#define COMPUTE(Ab, Bb) do {                                                 \
    _Pragma("unroll") for (int kk = 0; kk < 2; ++kk) {                       \
        bf16x8 a[4], b[4];                                                   \
        int sw = (((kk * 4 + g) ^ ln7) << 3);                                \
        _Pragma("unroll") for (int n = 0; n < 4; ++n)                        \
            b[n] = *(const bf16x8*)((Bb) + (wc * 64 + n * 16 + ln15) * 64 + sw); \
        _Pragma("unroll") for (int m = 0; m < 4; ++m)                        \
            a[m] = *(const bf16x8*)((Ab) + (wr * 64 + m * 16 + ln15) * 64 + sw); \
        __builtin_amdgcn_s_setprio(1);                                       \
        _Pragma("unroll") for (int m = 0; m < 4; ++m)                        \
            _Pragma("unroll") for (int n = 0; n < 4; ++n)                    \
                acc[m][n] = __builtin_amdgcn_mfma_f32_16x16x32_bf16(a[m], b[n], acc[m][n], 0, 0, 0); \
        __builtin_amdgcn_s_setprio(0);                                       \
    } } while (0)

#define FENCE() __builtin_amdgcn_sched_barrier(0)
#define DRAIN() asm volatile("s_waitcnt vmcnt(0)" ::: "memory")
#define BARR()  do { FENCE(); __builtin_amdgcn_s_barrier(); FENCE(); } while (0)

    STAGE(Ah0, Bh0, 0);
    DRAIN(); BARR();

    for (int kt = 0; kt < NT; kt += 2) {
        if (kt + 1 < NT) STAGE(Ah1, Bh1, (kt + 1) * 64);
        COMPUTE(Ah0, Bh0);
        DRAIN(); BARR();
        if (kt + 2 < NT) STAGE(Ah0, Bh0, (kt + 2) * 64);
        COMPUTE(Ah1, Bh1);
        DRAIN(); BARR();
    }
#undef STAGE
#undef COMPUTE
#undef FENCE
#undef DRAIN
#undef BARR

    // epilogue
    int l4 = lane >> 4;
    float bs[4];
#pragma unroll
    for (int n = 0; n < 4; ++n)
        bs[n] = bias[e * N + n0 + wc * 64 + n * 16 + ln15];
#pragma unroll
    for (int m = 0; m < 4; ++m) {
#pragma unroll
        for (int j = 0; j < 4; ++j) {
            int grow = m0 + wr * 64 + m * 16 + l4 * 4 + j;
            if (grow >= cnt) continue;
            if constexpr (MODE == 0) {
#pragma unroll
                for (int n = 0; n < 4; ++n) {
                    int gcol = n0 + wc * 64 + n * 16 + ln15;
                    float v = acc[m][n][j] + bs[n];
                    Hout[(size_t)(base + grow) * DFF + gcol] = (bf16_t)fmaxf(v, 0.f);
                }
            } else {
                float gt = gate_tok[list[grow]];
#pragma unroll
                for (int n = 0; n < 4; ++n) {
                    int gcol = n0 + wc * 64 + n * 16 + ln15;
                    Yp[(size_t)(base + grow) * DIM + gcol] = gt * (acc[m][n][j] + bs[n]);
                }
            }
        }
    }
}

// ---------------- combine: out[t] = Yp[inv[2t]] + Yp[inv[2t+1]], 2 rows/block ----------------
__global__ __launch_bounds__(256) void combine_kernel(
    const float* __restrict__ Yp, const int* __restrict__ inv,
    float* __restrict__ out)
{
#pragma unroll
    for (int q = 0; q < 2; ++q) {
        int t = blockIdx.x * 2 + q;
        int p0 = inv[2 * t], p1 = inv[2 * t + 1];
        const float4* a = (const float4*)(Yp + (size_t)p0 * DIM);
        const float4* b = (const float4*)(Yp + (size_t)p1 * DIM);
        float4* o = (float4*)(out + (size_t)t * DIM);
        int i = threadIdx.x;
        float4 va = a[i], vb = b[i];
        o[i] = make_float4(va.x + vb.x, va.y + vb.y, va.z + vb.z, va.w + vb.w);
    }
}

extern "C" void kernel_launch(void* const* d_in, const int* in_sizes, int n_in,
                              void* d_out, int out_size, void* d_ws, size_t ws_size,
                              hipStream_t stream) {
    const float* x       = (const float*)d_in[0];
    const float* noise   = (const float*)d_in[1];
    const float* w_route = (const float*)d_in[2];
    const float* b_route = (const float*)d_in[3];
    const float* w_noise = (const float*)d_in[4];
    const float* b_noise = (const float*)d_in[5];
    const float* w1      = (const float*)d_in[6];
    const float* b1      = (const float*)d_in[7];
    const float* w2      = (const float*)d_in[8];
    const float* b2      = (const float*)d_in[9];
    float* out = (float*)d_out;

    char* ws = (char*)d_ws;
    size_t off = 0;
    auto alloc = [&](size_t bytes) {
        off = (off + 255) & ~(size_t)255;
        size_t r = off; off += bytes; return r;
    };
    int*    counts   = (int*)   (ws + alloc(32));
    int*    lists    = (int*)   (ws + alloc((size_t)NEXP * T_TOK * 4));
    float*  gate_tok = (float*) (ws + alloc((size_t)T_TOK * 2 * 4));
    int*    inv      = (int*)   (ws + alloc((size_t)T_TOK * 2 * 4));
    bf16_t* w1t      = (bf16_t*)(ws + alloc((size_t)NEXP * DFF * DIM * 2));
    bf16_t* w2t      = (bf16_t*)(ws + alloc((size_t)NEXP * DIM * DFF * 2));
    bf16_t* Ap       = (bf16_t*)(ws + alloc((size_t)T_TOK * 2 * DIM * 2));
    bf16_t* H        = (bf16_t*)(ws + alloc((size_t)T_TOK * 2 * DFF * 2));
    float*  Yp       = (float*)w1t;   // w1t dead after GEMM1
    (void)ws_size; (void)in_sizes; (void)n_in; (void)out_size;

    hipMemsetAsync(counts, 0, 32, stream);

    transpose_cvt_kernel<<<dim3(DFF / 64, DIM / 64, NEXP), 256, 0, stream>>>(w1, w1t, DIM, DFF);
    transpose_cvt_kernel<<<dim3(DIM / 64, DFF / 64, NEXP), 256, 0, stream>>>(w2, w2t, DFF, DIM);

    router_kernel<<<T_TOK / 4, 256, 0, stream>>>(x, noise, w_route, b_route, w_noise, b_noise,
                                                 counts, lists, gate_tok);
    pack_a_kernel<<<T_TOK * 2 / 4, 256, 0, stream>>>(x, counts, lists, Ap, inv);

    moe_gemm_kernel<DIM, 0><<<dim3(64, DFF / 128, NEXP), 256, 0, stream>>>(
        Ap, w1t, b1, counts, lists, gate_tok, H, nullptr);
    moe_gemm_kernel<DFF, 1><<<dim3(64, DIM / 128, NEXP), 256, 0, stream>>>(
        H, w2t, b2, counts, lists, gate_tok, nullptr, Yp);

    combine_kernel<<<T_TOK / 2, 256, 0, stream>>>(Yp, inv, out);
}

// Round 14
// 763.840 us; speedup vs baseline: 1.3425x; 1.0692x over previous
//
#include <hip/hip_runtime.h>

typedef __bf16 bf16_t;
typedef __bf16 bf16x8 __attribute__((ext_vector_type(8)));
typedef __bf16 bf16x4 __attribute__((ext_vector_type(4)));
typedef float  f32x4  __attribute__((ext_vector_type(4)));

#define T_TOK 8192
#define DIM   1024
#define DFF   4096
#define NEXP  8

__device__ __forceinline__ void gll16(const void* g, void* l) {
    __builtin_amdgcn_global_load_lds(
        (const __attribute__((address_space(1))) char*)g,
        (__attribute__((address_space(3))) char*)l, 16, 0, 0);
}

// ---------------- fused transpose+convert for BOTH weights + counts init ----------------
// block id < 8192: w1 ([DIM][DFF] -> w1t [e][DFF][DIM]); else w2 ([DFF][DIM] -> w2t).
// 64x64 tile via LDS [64][65]; f32x4 reads, bf16x8 writes (r11-proven body).
__device__ __forceinline__ void transpose_tile(
    const float* __restrict__ src, bf16_t* __restrict__ dst,
    int R, int C, int r0, int c0, int tid, float (*t)[65])
{
    {
        int cg = tid & 15, r = tid >> 4;
#pragma unroll
        for (int i = 0; i < 4; ++i) {
            int rr = r + i * 16;
            float4 v = *(const float4*)&src[(size_t)(r0 + rr) * C + c0 + cg * 4];
            t[rr][cg * 4 + 0] = v.x; t[rr][cg * 4 + 1] = v.y;
            t[rr][cg * 4 + 2] = v.z; t[rr][cg * 4 + 3] = v.w;
        }
    }
    __syncthreads();
    {
        int rr = tid & 7, c = tid >> 3;
#pragma unroll
        for (int i = 0; i < 2; ++i) {
            int cc = c + i * 32;
            bf16x8 o;
#pragma unroll
            for (int j = 0; j < 8; ++j) o[j] = (bf16_t)t[rr * 8 + j][cc];
            *(bf16x8*)&dst[(size_t)(c0 + cc) * R + r0 + rr * 8] = o;
        }
    }
}

__global__ __launch_bounds__(256) void transpose_both_kernel(
    const float* __restrict__ w1, const float* __restrict__ w2,
    bf16_t* __restrict__ w1t, bf16_t* __restrict__ w2t,
    int* __restrict__ counts)
{
    __shared__ float t[64][65];
    int id = blockIdx.x;
    int tid = threadIdx.x;
    if (id == 0 && tid < NEXP) counts[tid] = 0;
    if (id < 8192) {
        // w1: R=DIM, C=DFF; 1024 blocks/expert: bx 0..63, by 0..15
        int e = id >> 10, rem = id & 1023;
        int bx = rem & 63, by = rem >> 6;
        transpose_tile(w1 + (size_t)e * DIM * DFF, w1t + (size_t)e * DIM * DFF,
                       DIM, DFF, by * 64, bx * 64, tid, t);
    } else {
        // w2: R=DFF, C=DIM; 1024 blocks/expert: bx 0..15, by 0..63
        int id2 = id - 8192;
        int e = id2 >> 10, rem = id2 & 1023;
        int bx = rem & 15, by = rem >> 4;
        transpose_tile(w2 + (size_t)e * DFF * DIM, w2t + (size_t)e * DFF * DIM,
                       DFF, DIM, by * 64, bx * 64, tid, t);
    }
}

// ---------------- router: wave per token, f64 accumulation ----------------
__global__ __launch_bounds__(256) void router_kernel(
    const float* __restrict__ x, const float* __restrict__ noise,
    const float* __restrict__ w_route, const float* __restrict__ b_route,
    const float* __restrict__ w_noise, const float* __restrict__ b_noise,
    int* __restrict__ counts, int* __restrict__ lists, float* __restrict__ gate_tok)
{
    int wave = threadIdx.x >> 6;
    int lane = threadIdx.x & 63;
    int t = blockIdx.x * 4 + wave;
    if (t >= T_TOK) return;

    const float* xr = x + (size_t)t * DIM;
    double aR[NEXP], aN[NEXP];
#pragma unroll
    for (int e = 0; e < NEXP; ++e) { aR[e] = 0.0; aN[e] = 0.0; }

#pragma unroll 4
    for (int i = 0; i < 16; ++i) {
        int k = lane + i * 64;
        double xv = (double)xr[k];
        const float4* wr4 = (const float4*)(w_route + (size_t)k * 8);
        const float4* wn4 = (const float4*)(w_noise + (size_t)k * 8);
        float4 r0 = wr4[0], r1 = wr4[1];
        float4 n0 = wn4[0], n1 = wn4[1];
        aR[0] += xv * (double)r0.x; aR[1] += xv * (double)r0.y;
        aR[2] += xv * (double)r0.z; aR[3] += xv * (double)r0.w;
        aR[4] += xv * (double)r1.x; aR[5] += xv * (double)r1.y;
        aR[6] += xv * (double)r1.z; aR[7] += xv * (double)r1.w;
        aN[0] += xv * (double)n0.x; aN[1] += xv * (double)n0.y;
        aN[2] += xv * (double)n0.z; aN[3] += xv * (double)n0.w;
        aN[4] += xv * (double)n1.x; aN[5] += xv * (double)n1.y;
        aN[6] += xv * (double)n1.z; aN[7] += xv * (double)n1.w;
    }
#pragma unroll
    for (int e = 0; e < NEXP; ++e) {
        for (int s = 1; s < 64; s <<= 1) {
            aR[e] += __shfl_xor(aR[e], s);
            aN[e] += __shfl_xor(aN[e], s);
        }
    }
    if (lane == 0) {
        double nv[NEXP];
#pragma unroll
        for (int e = 0; e < NEXP; ++e) {
            double lg = aR[e] + (double)b_route[e];
            double nl = aN[e] + (double)b_noise[e];
            double sp = (nl > 30.0) ? nl : log1p(exp(nl));
            nv[e] = lg + (double)noise[(size_t)t * 8 + e] * sp;
        }
        int i1 = 0;
#pragma unroll
        for (int e = 1; e < NEXP; ++e) if (nv[e] > nv[i1]) i1 = e;
        int i2 = (i1 == 0) ? 1 : 0;
#pragma unroll
        for (int e = 0; e < NEXP; ++e) if (e != i1 && nv[e] > nv[i2]) i2 = e;
        double m = nv[i1];
        double e2 = exp(nv[i2] - m);
        double s = 1.0 + e2;
        gate_tok[2 * t + 0] = (float)(1.0 / s);
        gate_tok[2 * t + 1] = (float)(e2 / s);
        int p1 = atomicAdd(&counts[i1], 1);
        lists[i1 * T_TOK + p1] = 2 * t + 0;
        int p2 = atomicAdd(&counts[i2], 1);
        lists[i2 * T_TOK + p2] = 2 * t + 1;
    }
}

// ---------------- prefix: bases[e] = exclusive prefix sum of counts ----------------
__global__ void prefix_kernel(const int* __restrict__ counts, int* __restrict__ bases) {
    if (threadIdx.x == 0 && blockIdx.x == 0) {
        int s = 0;
#pragma unroll
        for (int e = 0; e < NEXP; ++e) { bases[e] = s; s += counts[e]; }
    }
}

// ---------------- pack A: flat over the 16384 packed rows ----------------
__global__ __launch_bounds__(256) void pack_a_kernel(
    const float* __restrict__ x, const int* __restrict__ bases,
    const int* __restrict__ lists, bf16_t* __restrict__ Ap, int* __restrict__ inv)
{
    int wave = threadIdx.x >> 6, lane = threadIdx.x & 63;
    int p = blockIdx.x * 4 + wave;
    int e = 0;
#pragma unroll
    for (int i = 1; i < NEXP; ++i) e += (p >= bases[i]);
    int pos = p - bases[e];
    int entry = lists[e * T_TOK + pos];
    if (lane == 0) inv[entry] = p;
    const float4* src = (const float4*)(x + (size_t)(entry >> 1) * DIM);
    bf16x4* dst = (bf16x4*)(Ap + (size_t)p * DIM);
#pragma unroll
    for (int j = 0; j < 4; ++j) {
        float4 v = src[lane + j * 64];
        bf16x4 o;
        o[0] = (bf16_t)v.x; o[1] = (bf16_t)v.y; o[2] = (bf16_t)v.z; o[3] = (bf16_t)v.w;
        dst[lane + j * 64] = o;
    }
}

// ---------------- grouped GEMM: 128x128 tile, BK=64, 4 waves, counted-vmcnt dbuf ----------------
// r11 VERBATIM (best measured: 239us/GEMM): 64KB LDS -> 2 blocks/CU + XCD
// expert-clustering (e = wg&7) + two-barrier loop with counted s_waitcnt
// vmcnt(8) + T2 swizzle + T5 setprio. Only change: MODE 1 writes Yp as bf16.
template<int K, int MODE>
__global__ __launch_bounds__(256) void moe_gemm_kernel(
    const bf16_t* __restrict__ Asrc, const bf16_t* __restrict__ Wt,
    const float* __restrict__ bias,
    const int* __restrict__ counts, const int* __restrict__ bases,
    const int* __restrict__ lists, const float* __restrict__ gate_tok,
    bf16_t* __restrict__ Hout, bf16_t* __restrict__ Yp)
{
    constexpr int N = (MODE == 0) ? DFF : DIM;
    constexpr int NT = K / 64;
    constexpr int NY = N / 128;

    int wg = blockIdx.x + 64 * (blockIdx.y + NY * blockIdx.z);
    int e = wg & 7;
    int inner = wg >> 3;
    int xi = inner & 63;
    int yi = inner >> 6;

    int cnt = counts[e];
    int m0 = xi * 128;
    if (m0 >= cnt) return;
    int base = bases[e];
    int n0 = yi * 128;
    const int* list = lists + e * T_TOK;
    const bf16_t* W = Wt + (size_t)e * N * K;

    __shared__ __attribute__((aligned(16))) bf16_t Ah0[128 * 64];
    __shared__ __attribute__((aligned(16))) bf16_t Bh0[128 * 64];
    __shared__ __attribute__((aligned(16))) bf16_t Ah1[128 * 64];
    __shared__ __attribute__((aligned(16))) bf16_t Bh1[128 * 64];

    int tid = threadIdx.x;
    int lane = tid & 63;
    int wave = tid >> 6;
    int wr = wave >> 1, wc = wave & 1;

    int kcs = (((lane & 7) ^ (lane >> 3)) << 3);
    const bf16_t* pA[4];
    const bf16_t* pB[4];
#pragma unroll
    for (int i = 0; i < 4; ++i) {
        int c = wave * 4 + i;
        int r = c * 8 + (lane >> 3);
        int ridx = m0 + r; if (ridx > cnt - 1) ridx = cnt - 1;
        pA[i] = Asrc + (size_t)(base + ridx) * K + kcs;
        pB[i] = W + (size_t)(n0 + r) * K + kcs;
    }

    f32x4 acc[4][4];
#pragma unroll
    for (int m = 0; m < 4; ++m)
#pragma unroll
        for (int n = 0; n < 4; ++n)
            acc[m][n] = (f32x4){0.f, 0.f, 0.f, 0.f};

    int g = lane >> 4, ln15 = lane & 15, ln7 = lane & 7;

#define STAGE(An, Bn, k0) do {                                               \
    _Pragma("unroll") for (int i = 0; i < 4; ++i) {                          \
        int c = wave * 4 + i;                                                \
        gll16(pA[i] + (k0), (An) + c * 512);                                 \
        gll16(pB[i] + (k0), (Bn) + c * 512);                                 \
    } } while (0)

#define COMPUTE(Ab, Bb) do {                                                 \
    _Pragma("unroll") for (int kk = 0; kk < 2; ++kk) {                       \
        bf16x8 a[4], b[4];                                                   \
        int sw = (((kk * 4 + g) ^ ln7) << 3);                                \
        _Pragma("unroll") for (int n = 0; n < 4; ++n)                        \
            b[n] = *(const bf16x8*)((Bb) + (wc * 64 + n * 16 + ln15) * 64 + sw); \
        _Pragma("unroll") for (int m = 0; m < 4; ++m)                        \
            a[m] = *(const bf16x8*)((Ab) + (wr * 64 + m * 16 + ln15) * 64 + sw); \
        __builtin_amdgcn_s_setprio(1);                                       \
        _Pragma("unroll") for (int m = 0; m < 4; ++m)                        \
            _Pragma("unroll") for (int n = 0; n < 4; ++n)                    \
                acc[m][n] = __builtin_amdgcn_mfma_f32_16x16x32_bf16(a[m], b[n], acc[m][n], 0, 0, 0); \
        __builtin_amdgcn_s_setprio(0);                                       \
    } } while (0)

#define FENCE() __builtin_amdgcn_sched_barrier(0)
#define WAITV(n) asm volatile("s_waitcnt vmcnt(" #n ")" ::: "memory")

    STAGE(Ah0, Bh0, 0);

    for (int kt = 0; kt < NT; kt += 2) {
        if (kt + 1 < NT) { STAGE(Ah1, Bh1, (kt + 1) * 64); WAITV(8); }
        else             { WAITV(0); }
        FENCE(); __builtin_amdgcn_s_barrier(); FENCE();
        COMPUTE(Ah0, Bh0);
        FENCE(); __builtin_amdgcn_s_barrier(); FENCE();
        if (kt + 2 < NT) { STAGE(Ah0, Bh0, (kt + 2) * 64); WAITV(8); }
        else             { WAITV(0); }
        FENCE(); __builtin_amdgcn_s_barrier(); FENCE();
        COMPUTE(Ah1, Bh1);
        FENCE(); __builtin_amdgcn_s_barrier(); FENCE();
    }
#undef STAGE
#undef COMPUTE
#undef FENCE
#undef WAITV

    int l4 = lane >> 4;
    float bs[4];
#pragma unroll
    for (int n = 0; n < 4; ++n)
        bs[n] = bias[e * N + n0 + wc * 64 + n * 16 + ln15];
#pragma unroll
    for (int m = 0; m < 4; ++m) {
#pragma unroll
        for (int j = 0; j < 4; ++j) {
            int grow = m0 + wr * 64 + m * 16 + l4 * 4 + j;
            if (grow >= cnt) continue;
            if constexpr (MODE == 0) {
#pragma unroll
                for (int n = 0; n < 4; ++n) {
                    int gcol = n0 + wc * 64 + n * 16 + ln15;
                    float v = acc[m][n][j] + bs[n];
                    Hout[(size_t)(base + grow) * DFF + gcol] = (bf16_t)fmaxf(v, 0.f);
                }
            } else {
                float gt = gate_tok[list[grow]];
#pragma unroll
                for (int n = 0; n < 4; ++n) {
                    int gcol = n0 + wc * 64 + n * 16 + ln15;
                    Yp[(size_t)(base + grow) * DIM + gcol] = (bf16_t)(gt * (acc[m][n][j] + bs[n]));
                }
            }
        }
    }
}

// ---------------- combine: out[t] = Yp[inv[2t]] + Yp[inv[2t+1]] (bf16 Yp), 2 rows/block ----------------
__global__ __launch_bounds__(256) void combine_kernel(
    const bf16_t* __restrict__ Yp, const int* __restrict__ inv,
    float* __restrict__ out)
{
#pragma unroll
    for (int q = 0; q < 2; ++q) {
        int t = blockIdx.x * 2 + q;
        int p0 = inv[2 * t], p1 = inv[2 * t + 1];
        const bf16x4* a = (const bf16x4*)(Yp + (size_t)p0 * DIM);
        const bf16x4* b = (const bf16x4*)(Yp + (size_t)p1 * DIM);
        float4* o = (float4*)(out + (size_t)t * DIM);
        int i = threadIdx.x;
        bf16x4 va = a[i], vb = b[i];
        o[i] = make_float4((float)va[0] + (float)vb[0], (float)va[1] + (float)vb[1],
                           (float)va[2] + (float)vb[2], (float)va[3] + (float)vb[3]);
    }
}

extern "C" void kernel_launch(void* const* d_in, const int* in_sizes, int n_in,
                              void* d_out, int out_size, void* d_ws, size_t ws_size,
                              hipStream_t stream) {
    const float* x       = (const float*)d_in[0];
    const float* noise   = (const float*)d_in[1];
    const float* w_route = (const float*)d_in[2];
    const float* b_route = (const float*)d_in[3];
    const float* w_noise = (const float*)d_in[4];
    const float* b_noise = (const float*)d_in[5];
    const float* w1      = (const float*)d_in[6];
    const float* b1      = (const float*)d_in[7];
    const float* w2      = (const float*)d_in[8];
    const float* b2      = (const float*)d_in[9];
    float* out = (float*)d_out;

    char* ws = (char*)d_ws;
    size_t off = 0;
    auto alloc = [&](size_t bytes) {
        off = (off + 255) & ~(size_t)255;
        size_t r = off; off += bytes; return r;
    };
    int*    counts   = (int*)   (ws + alloc(32));
    int*    bases    = (int*)   (ws + alloc(32));
    int*    lists    = (int*)   (ws + alloc((size_t)NEXP * T_TOK * 4));
    float*  gate_tok = (float*) (ws + alloc((size_t)T_TOK * 2 * 4));
    int*    inv      = (int*)   (ws + alloc((size_t)T_TOK * 2 * 4));
    bf16_t* w1t      = (bf16_t*)(ws + alloc((size_t)NEXP * DFF * DIM * 2));
    bf16_t* w2t      = (bf16_t*)(ws + alloc((size_t)NEXP * DIM * DFF * 2));
    bf16_t* Ap       = (bf16_t*)(ws + alloc((size_t)T_TOK * 2 * DIM * 2));
    bf16_t* H        = (bf16_t*)(ws + alloc((size_t)T_TOK * 2 * DFF * 2));
    bf16_t* Yp       = w1t;   // w1t (64MB) dead after GEMM1; Yp bf16 (32MB)
    (void)ws_size; (void)in_sizes; (void)n_in; (void)out_size;

    // counts zeroing folded into transpose_both_kernel (block 0).
    transpose_both_kernel<<<16384, 256, 0, stream>>>(w1, w2, w1t, w2t, counts);

    router_kernel<<<T_TOK / 4, 256, 0, stream>>>(x, noise, w_route, b_route, w_noise, b_noise,
                                                 counts, lists, gate_tok);
    prefix_kernel<<<1, 64, 0, stream>>>(counts, bases);
    pack_a_kernel<<<T_TOK * 2 / 4, 256, 0, stream>>>(x, bases, lists, Ap, inv);

    moe_gemm_kernel<DIM, 0><<<dim3(64, DFF / 128, NEXP), 256, 0, stream>>>(
        Ap, w1t, b1, counts, bases, lists, gate_tok, H, nullptr);
    moe_gemm_kernel<DFF, 1><<<dim3(64, DIM / 128, NEXP), 256, 0, stream>>>(
        H, w2t, b2, counts, bases, lists, gate_tok, nullptr, Yp);

    combine_kernel<<<T_TOK / 2, 256, 0, stream>>>(Yp, inv, out);
}

// Round 15
// 742.126 us; speedup vs baseline: 1.3817x; 1.0293x over previous
//
#include <hip/hip_runtime.h>

typedef __bf16 bf16_t;
typedef __bf16 bf16x8 __attribute__((ext_vector_type(8)));
typedef __bf16 bf16x4 __attribute__((ext_vector_type(4)));
typedef float  f32x4  __attribute__((ext_vector_type(4)));

#define T_TOK 8192
#define DIM   1024
#define DFF   4096
#define NEXP  8

__device__ __forceinline__ void gll16(const void* g, void* l) {
    __builtin_amdgcn_global_load_lds(
        (const __attribute__((address_space(1))) char*)g,
        (__attribute__((address_space(3))) char*)l, 16, 0, 0);
}

// ---------------- transpose tile helper (r14-proven body) ----------------
__device__ __forceinline__ void transpose_tile(
    const float* __restrict__ src, bf16_t* __restrict__ dst,
    int R, int C, int r0, int c0, int tid, float (*t)[65])
{
    {
        int cg = tid & 15, r = tid >> 4;
#pragma unroll
        for (int i = 0; i < 4; ++i) {
            int rr = r + i * 16;
            float4 v = *(const float4*)&src[(size_t)(r0 + rr) * C + c0 + cg * 4];
            t[rr][cg * 4 + 0] = v.x; t[rr][cg * 4 + 1] = v.y;
            t[rr][cg * 4 + 2] = v.z; t[rr][cg * 4 + 3] = v.w;
        }
    }
    __syncthreads();
    {
        int rr = tid & 7, c = tid >> 3;
#pragma unroll
        for (int i = 0; i < 2; ++i) {
            int cc = c + i * 32;
            bf16x8 o;
#pragma unroll
            for (int j = 0; j < 8; ++j) o[j] = (bf16_t)t[rr * 8 + j][cc];
            *(bf16x8*)&dst[(size_t)(c0 + cc) * R + r0 + rr * 8] = o;
        }
    }
}

// ---------------- fused prologue: router (blocks 0..2047, dispatched FIRST so it
// overlaps the BW-bound transposes) + w1 transpose (2048..10239) + w2 (10240..18431).
// Disjoint data: router reads x/noise/route-weights, transposes read w1/w2.
__global__ __launch_bounds__(256) void fused_pre_kernel(
    const float* __restrict__ x, const float* __restrict__ noise,
    const float* __restrict__ w_route, const float* __restrict__ b_route,
    const float* __restrict__ w_noise, const float* __restrict__ b_noise,
    const float* __restrict__ w1, const float* __restrict__ w2,
    bf16_t* __restrict__ w1t, bf16_t* __restrict__ w2t,
    int* __restrict__ counts, int* __restrict__ lists, float* __restrict__ gate_tok)
{
    __shared__ float t[64][65];
    int id = blockIdx.x;
    int tid = threadIdx.x;

    if (id >= 2048) {
        if (id < 10240) {
            int t1 = id - 2048;
            int e = t1 >> 10, rem = t1 & 1023;
            int bx = rem & 63, by = rem >> 6;           // DFF/64=64 x, DIM/64=16 y
            transpose_tile(w1 + (size_t)e * DIM * DFF, w1t + (size_t)e * DIM * DFF,
                           DIM, DFF, by * 64, bx * 64, tid, t);
        } else {
            int t2 = id - 10240;
            int e = t2 >> 10, rem = t2 & 1023;
            int bx = rem & 15, by = rem >> 4;           // DIM/64=16 x, DFF/64=64 y
            transpose_tile(w2 + (size_t)e * DFF * DIM, w2t + (size_t)e * DFF * DIM,
                           DFF, DIM, by * 64, bx * 64, tid, t);
        }
        return;
    }

    // ---- router: wave per token, f64 accumulation (r14 verbatim) ----
    int wave = tid >> 6;
    int lane = tid & 63;
    int tok = id * 4 + wave;
    if (tok >= T_TOK) return;

    const float* xr = x + (size_t)tok * DIM;
    double aR[NEXP], aN[NEXP];
#pragma unroll
    for (int e = 0; e < NEXP; ++e) { aR[e] = 0.0; aN[e] = 0.0; }

#pragma unroll 4
    for (int i = 0; i < 16; ++i) {
        int k = lane + i * 64;
        double xv = (double)xr[k];
        const float4* wr4 = (const float4*)(w_route + (size_t)k * 8);
        const float4* wn4 = (const float4*)(w_noise + (size_t)k * 8);
        float4 r0 = wr4[0], r1 = wr4[1];
        float4 n0 = wn4[0], n1 = wn4[1];
        aR[0] += xv * (double)r0.x; aR[1] += xv * (double)r0.y;
        aR[2] += xv * (double)r0.z; aR[3] += xv * (double)r0.w;
        aR[4] += xv * (double)r1.x; aR[5] += xv * (double)r1.y;
        aR[6] += xv * (double)r1.z; aR[7] += xv * (double)r1.w;
        aN[0] += xv * (double)n0.x; aN[1] += xv * (double)n0.y;
        aN[2] += xv * (double)n0.z; aN[3] += xv * (double)n0.w;
        aN[4] += xv * (double)n1.x; aN[5] += xv * (double)n1.y;
        aN[6] += xv * (double)n1.z; aN[7] += xv * (double)n1.w;
    }
#pragma unroll
    for (int e = 0; e < NEXP; ++e) {
        for (int s = 1; s < 64; s <<= 1) {
            aR[e] += __shfl_xor(aR[e], s);
            aN[e] += __shfl_xor(aN[e], s);
        }
    }
    if (lane == 0) {
        double nv[NEXP];
#pragma unroll
        for (int e = 0; e < NEXP; ++e) {
            double lg = aR[e] + (double)b_route[e];
            double nl = aN[e] + (double)b_noise[e];
            double sp = (nl > 30.0) ? nl : log1p(exp(nl));
            nv[e] = lg + (double)noise[(size_t)tok * 8 + e] * sp;
        }
        int i1 = 0;
#pragma unroll
        for (int e = 1; e < NEXP; ++e) if (nv[e] > nv[i1]) i1 = e;
        int i2 = (i1 == 0) ? 1 : 0;
#pragma unroll
        for (int e = 0; e < NEXP; ++e) if (e != i1 && nv[e] > nv[i2]) i2 = e;
        double m = nv[i1];
        double e2 = exp(nv[i2] - m);
        double s = 1.0 + e2;
        gate_tok[2 * tok + 0] = (float)(1.0 / s);
        gate_tok[2 * tok + 1] = (float)(e2 / s);
        int p1 = atomicAdd(&counts[i1], 1);
        lists[i1 * T_TOK + p1] = 2 * tok + 0;
        int p2 = atomicAdd(&counts[i2], 1);
        lists[i2 * T_TOK + p2] = 2 * tok + 1;
    }
}

// ---------------- prefix: bases[e] = exclusive prefix sum of counts ----------------
__global__ void prefix_kernel(const int* __restrict__ counts, int* __restrict__ bases) {
    if (threadIdx.x == 0 && blockIdx.x == 0) {
        int s = 0;
#pragma unroll
        for (int e = 0; e < NEXP; ++e) { bases[e] = s; s += counts[e]; }
    }
}

// ---------------- pack A: flat over the 16384 packed rows ----------------
__global__ __launch_bounds__(256) void pack_a_kernel(
    const float* __restrict__ x, const int* __restrict__ bases,
    const int* __restrict__ lists, bf16_t* __restrict__ Ap, int* __restrict__ inv)
{
    int wave = threadIdx.x >> 6, lane = threadIdx.x & 63;
    int p = blockIdx.x * 4 + wave;
    int e = 0;
#pragma unroll
    for (int i = 1; i < NEXP; ++i) e += (p >= bases[i]);
    int pos = p - bases[e];
    int entry = lists[e * T_TOK + pos];
    if (lane == 0) inv[entry] = p;
    const float4* src = (const float4*)(x + (size_t)(entry >> 1) * DIM);
    bf16x4* dst = (bf16x4*)(Ap + (size_t)p * DIM);
#pragma unroll
    for (int j = 0; j < 4; ++j) {
        float4 v = src[lane + j * 64];
        bf16x4 o;
        o[0] = (bf16_t)v.x; o[1] = (bf16_t)v.y; o[2] = (bf16_t)v.z; o[3] = (bf16_t)v.w;
        dst[lane + j * 64] = o;
    }
}

// ---------------- grouped GEMM: 128x128 tile, BK=64, 4 waves, counted-vmcnt dbuf ----------------
// r14 VERBATIM (239us/GEMM measured): 64KB LDS -> 2 blocks/CU + XCD
// expert-clustering (e = wg&7) + two-barrier loop with counted s_waitcnt
// vmcnt(8) + T2 swizzle + T5 setprio. MODE 1 writes Yp as bf16.
template<int K, int MODE>
__global__ __launch_bounds__(256) void moe_gemm_kernel(
    const bf16_t* __restrict__ Asrc, const bf16_t* __restrict__ Wt,
    const float* __restrict__ bias,
    const int* __restrict__ counts, const int* __restrict__ bases,
    const int* __restrict__ lists, const float* __restrict__ gate_tok,
    bf16_t* __restrict__ Hout, bf16_t* __restrict__ Yp)
{
    constexpr int N = (MODE == 0) ? DFF : DIM;
    constexpr int NT = K / 64;
    constexpr int NY = N / 128;

    int wg = blockIdx.x + 64 * (blockIdx.y + NY * blockIdx.z);
    int e = wg & 7;
    int inner = wg >> 3;
    int xi = inner & 63;
    int yi = inner >> 6;

    int cnt = counts[e];
    int m0 = xi * 128;
    if (m0 >= cnt) return;
    int base = bases[e];
    int n0 = yi * 128;
    const int* list = lists + e * T_TOK;
    const bf16_t* W = Wt + (size_t)e * N * K;

    __shared__ __attribute__((aligned(16))) bf16_t Ah0[128 * 64];
    __shared__ __attribute__((aligned(16))) bf16_t Bh0[128 * 64];
    __shared__ __attribute__((aligned(16))) bf16_t Ah1[128 * 64];
    __shared__ __attribute__((aligned(16))) bf16_t Bh1[128 * 64];

    int tid = threadIdx.x;
    int lane = tid & 63;
    int wave = tid >> 6;
    int wr = wave >> 1, wc = wave & 1;

    int kcs = (((lane & 7) ^ (lane >> 3)) << 3);
    const bf16_t* pA[4];
    const bf16_t* pB[4];
#pragma unroll
    for (int i = 0; i < 4; ++i) {
        int c = wave * 4 + i;
        int r = c * 8 + (lane >> 3);
        int ridx = m0 + r; if (ridx > cnt - 1) ridx = cnt - 1;
        pA[i] = Asrc + (size_t)(base + ridx) * K + kcs;
        pB[i] = W + (size_t)(n0 + r) * K + kcs;
    }

    f32x4 acc[4][4];
#pragma unroll
    for (int m = 0; m < 4; ++m)
#pragma unroll
        for (int n = 0; n < 4; ++n)
            acc[m][n] = (f32x4){0.f, 0.f, 0.f, 0.f};

    int g = lane >> 4, ln15 = lane & 15, ln7 = lane & 7;

#define STAGE(An, Bn, k0) do {                                               \
    _Pragma("unroll") for (int i = 0; i < 4; ++i) {                          \
        int c = wave * 4 + i;                                                \
        gll16(pA[i] + (k0), (An) + c * 512);                                 \
        gll16(pB[i] + (k0), (Bn) + c * 512);                                 \
    } } while (0)

#define COMPUTE(Ab, Bb) do {                                                 \
    _Pragma("unroll") for (int kk = 0; kk < 2; ++kk) {                       \
        bf16x8 a[4], b[4];                                                   \
        int sw = (((kk * 4 + g) ^ ln7) << 3);                                \
        _Pragma("unroll") for (int n = 0; n < 4; ++n)                        \
            b[n] = *(const bf16x8*)((Bb) + (wc * 64 + n * 16 + ln15) * 64 + sw); \
        _Pragma("unroll") for (int m = 0; m < 4; ++m)                        \
            a[m] = *(const bf16x8*)((Ab) + (wr * 64 + m * 16 + ln15) * 64 + sw); \
        __builtin_amdgcn_s_setprio(1);                                       \
        _Pragma("unroll") for (int m = 0; m < 4; ++m)                        \
            _Pragma("unroll") for (int n = 0; n < 4; ++n)                    \
                acc[m][n] = __builtin_amdgcn_mfma_f32_16x16x32_bf16(a[m], b[n], acc[m][n], 0, 0, 0); \
        __builtin_amdgcn_s_setprio(0);                                       \
    } } while (0)

#define FENCE() __builtin_amdgcn_sched_barrier(0)
#define WAITV(n) asm volatile("s_waitcnt vmcnt(" #n ")" ::: "memory")

    STAGE(Ah0, Bh0, 0);

    for (int kt = 0; kt < NT; kt += 2) {
        if (kt + 1 < NT) { STAGE(Ah1, Bh1, (kt + 1) * 64); WAITV(8); }
        else             { WAITV(0); }
        FENCE(); __builtin_amdgcn_s_barrier(); FENCE();
        COMPUTE(Ah0, Bh0);
        FENCE(); __builtin_amdgcn_s_barrier(); FENCE();
        if (kt + 2 < NT) { STAGE(Ah0, Bh0, (kt + 2) * 64); WAITV(8); }
        else             { WAITV(0); }
        FENCE(); __builtin_amdgcn_s_barrier(); FENCE();
        COMPUTE(Ah1, Bh1);
        FENCE(); __builtin_amdgcn_s_barrier(); FENCE();
    }
#undef STAGE
#undef COMPUTE
#undef FENCE
#undef WAITV

    int l4 = lane >> 4;
    float bs[4];
#pragma unroll
    for (int n = 0; n < 4; ++n)
        bs[n] = bias[e * N + n0 + wc * 64 + n * 16 + ln15];
#pragma unroll
    for (int m = 0; m < 4; ++m) {
#pragma unroll
        for (int j = 0; j < 4; ++j) {
            int grow = m0 + wr * 64 + m * 16 + l4 * 4 + j;
            if (grow >= cnt) continue;
            if constexpr (MODE == 0) {
#pragma unroll
                for (int n = 0; n < 4; ++n) {
                    int gcol = n0 + wc * 64 + n * 16 + ln15;
                    float v = acc[m][n][j] + bs[n];
                    Hout[(size_t)(base + grow) * DFF + gcol] = (bf16_t)fmaxf(v, 0.f);
                }
            } else {
                float gt = gate_tok[list[grow]];
#pragma unroll
                for (int n = 0; n < 4; ++n) {
                    int gcol = n0 + wc * 64 + n * 16 + ln15;
                    Yp[(size_t)(base + grow) * DIM + gcol] = (bf16_t)(gt * (acc[m][n][j] + bs[n]));
                }
            }
        }
    }
}

// ---------------- combine: out[t] = Yp[inv[2t]] + Yp[inv[2t+1]] (bf16 Yp), 2 rows/block ----------------
__global__ __launch_bounds__(256) void combine_kernel(
    const bf16_t* __restrict__ Yp, const int* __restrict__ inv,
    float* __restrict__ out)
{
#pragma unroll
    for (int q = 0; q < 2; ++q) {
        int t = blockIdx.x * 2 + q;
        int p0 = inv[2 * t], p1 = inv[2 * t + 1];
        const bf16x4* a = (const bf16x4*)(Yp + (size_t)p0 * DIM);
        const bf16x4* b = (const bf16x4*)(Yp + (size_t)p1 * DIM);
        float4* o = (float4*)(out + (size_t)t * DIM);
        int i = threadIdx.x;
        bf16x4 va = a[i], vb = b[i];
        o[i] = make_float4((float)va[0] + (float)vb[0], (float)va[1] + (float)vb[1],
                           (float)va[2] + (float)vb[2], (float)va[3] + (float)vb[3]);
    }
}

extern "C" void kernel_launch(void* const* d_in, const int* in_sizes, int n_in,
                              void* d_out, int out_size, void* d_ws, size_t ws_size,
                              hipStream_t stream) {
    const float* x       = (const float*)d_in[0];
    const float* noise   = (const float*)d_in[1];
    const float* w_route = (const float*)d_in[2];
    const float* b_route = (const float*)d_in[3];
    const float* w_noise = (const float*)d_in[4];
    const float* b_noise = (const float*)d_in[5];
    const float* w1      = (const float*)d_in[6];
    const float* b1      = (const float*)d_in[7];
    const float* w2      = (const float*)d_in[8];
    const float* b2      = (const float*)d_in[9];
    float* out = (float*)d_out;

    char* ws = (char*)d_ws;
    size_t off = 0;
    auto alloc = [&](size_t bytes) {
        off = (off + 255) & ~(size_t)255;
        size_t r = off; off += bytes; return r;
    };
    int*    counts   = (int*)   (ws + alloc(32));
    int*    bases    = (int*)   (ws + alloc(32));
    int*    lists    = (int*)   (ws + alloc((size_t)NEXP * T_TOK * 4));
    float*  gate_tok = (float*) (ws + alloc((size_t)T_TOK * 2 * 4));
    int*    inv      = (int*)   (ws + alloc((size_t)T_TOK * 2 * 4));
    bf16_t* w1t      = (bf16_t*)(ws + alloc((size_t)NEXP * DFF * DIM * 2));
    bf16_t* w2t      = (bf16_t*)(ws + alloc((size_t)NEXP * DIM * DFF * 2));
    bf16_t* Ap       = (bf16_t*)(ws + alloc((size_t)T_TOK * 2 * DIM * 2));
    bf16_t* H        = (bf16_t*)(ws + alloc((size_t)T_TOK * 2 * DFF * 2));
    bf16_t* Yp       = w1t;   // w1t (64MB) dead after GEMM1; Yp bf16 (32MB)
    (void)ws_size; (void)in_sizes; (void)n_in; (void)out_size;

    hipMemsetAsync(counts, 0, 32, stream);

    // router (blocks 0..2047, runs first) overlaps with both weight transposes.
    fused_pre_kernel<<<18432, 256, 0, stream>>>(x, noise, w_route, b_route, w_noise, b_noise,
                                                w1, w2, w1t, w2t, counts, lists, gate_tok);

    prefix_kernel<<<1, 64, 0, stream>>>(counts, bases);
    pack_a_kernel<<<T_TOK * 2 / 4, 256, 0, stream>>>(x, bases, lists, Ap, inv);

    moe_gemm_kernel<DIM, 0><<<dim3(64, DFF / 128, NEXP), 256, 0, stream>>>(
        Ap, w1t, b1, counts, bases, lists, gate_tok, H, nullptr);
    moe_gemm_kernel<DFF, 1><<<dim3(64, DIM / 128, NEXP), 256, 0, stream>>>(
        H, w2t, b2, counts, bases, lists, gate_tok, nullptr, Yp);

    combine_kernel<<<T_TOK / 2, 256, 0, stream>>>(Yp, inv, out);
}

// Round 16
// 740.468 us; speedup vs baseline: 1.3848x; 1.0022x over previous
//
#include <hip/hip_runtime.h>

typedef __bf16 bf16_t;
typedef __bf16 bf16x8 __attribute__((ext_vector_type(8)));
typedef __bf16 bf16x4 __attribute__((ext_vector_type(4)));
typedef __bf16 bf16x2 __attribute__((ext_vector_type(2)));
typedef float  f32x4  __attribute__((ext_vector_type(4)));
typedef unsigned int u32;
typedef u32 u32x4 __attribute__((ext_vector_type(4)));

#define T_TOK 8192
#define DIM   1024
#define DFF   4096
#define NEXP  8

__device__ __forceinline__ void gll16(const void* g, void* l) {
    __builtin_amdgcn_global_load_lds(
        (const __attribute__((address_space(1))) char*)g,
        (__attribute__((address_space(3))) char*)l, 16, 0, 0);
}

// ---------------- packed-pair transpose tile (64x64), u32 row-pair packing ----------------
// Read: per thread 4x float4 from rows (2p, 2p+1). Pack bf16 pairs into u32
// (low = even row => out elements [2p,2p+1] in order). LDS u32[64][32] = 8KB
// (20 blocks/CU vs 9). Write swizzle p' = p ^ (((c>>2)&7)<<2): per-instr banks
// 2-way (free, m136); preserves aligned 4-u32 runs so read side is b128.
// Read-back: 2x ds_read_b128 + 2x 128B contiguous global store per thread.
__device__ __forceinline__ void transpose_tile(
    const float* __restrict__ src, bf16_t* __restrict__ dst,
    int R, int C, int r0, int c0, int tid, u32* lds)
{
    {
        int cg = tid & 15, rp = tid >> 4;     // cg: 4-col group, rp: 0..15
#pragma unroll
        for (int i = 0; i < 2; ++i) {
            int p = rp + i * 16;              // row-pair 0..31
            f32x4 a = *(const f32x4*)&src[(size_t)(r0 + 2 * p) * C + c0 + cg * 4];
            f32x4 b = *(const f32x4*)&src[(size_t)(r0 + 2 * p + 1) * C + c0 + cg * 4];
#pragma unroll
            for (int j = 0; j < 4; ++j) {
                int c = cg * 4 + j;
                union { bf16x2 h; u32 w; } cv;
                cv.h[0] = (bf16_t)a[j];       // even row -> low 16 (element 2p)
                cv.h[1] = (bf16_t)b[j];       // odd row  -> high 16 (element 2p+1)
                int ps = p ^ (((c >> 2) & 7) << 2);
                lds[c * 32 + ps] = cv.w;
            }
        }
    }
    __syncthreads();
    {
        int q = tid & 7, ccb = tid >> 3;      // q: 16B segment, ccb: 0..31
#pragma unroll
        for (int i = 0; i < 2; ++i) {
            int cc = ccb + i * 32;            // out-row = source col
            int ps = (q * 4) ^ ((((cc) >> 2) & 7) << 2);
            u32x4 v = *(const u32x4*)&lds[cc * 32 + ps];
            *(u32x4*)&dst[(size_t)(c0 + cc) * R + r0 + q * 8] = v;
        }
    }
}

// ---------------- fused prologue: router (blocks 0..2047, dispatched FIRST) +
// w1 transpose (2048..10239) + w2 transpose (10240..18431). Disjoint data.
__global__ __launch_bounds__(256) void fused_pre_kernel(
    const float* __restrict__ x, const float* __restrict__ noise,
    const float* __restrict__ w_route, const float* __restrict__ b_route,
    const float* __restrict__ w_noise, const float* __restrict__ b_noise,
    const float* __restrict__ w1, const float* __restrict__ w2,
    bf16_t* __restrict__ w1t, bf16_t* __restrict__ w2t,
    int* __restrict__ counts, int* __restrict__ lists, float* __restrict__ gate_tok)
{
    __shared__ u32 lds[64 * 32];
    int id = blockIdx.x;
    int tid = threadIdx.x;

    if (id >= 2048) {
        if (id < 10240) {
            int t1 = id - 2048;
            int e = t1 >> 10, rem = t1 & 1023;
            int bx = rem & 63, by = rem >> 6;           // DFF/64=64 x, DIM/64=16 y
            transpose_tile(w1 + (size_t)e * DIM * DFF, w1t + (size_t)e * DIM * DFF,
                           DIM, DFF, by * 64, bx * 64, tid, lds);
        } else {
            int t2 = id - 10240;
            int e = t2 >> 10, rem = t2 & 1023;
            int bx = rem & 15, by = rem >> 4;           // DIM/64=16 x, DFF/64=64 y
            transpose_tile(w2 + (size_t)e * DFF * DIM, w2t + (size_t)e * DFF * DIM,
                           DFF, DIM, by * 64, bx * 64, tid, lds);
        }
        return;
    }

    // ---- router: wave per token, f64 accumulation (r14 verbatim) ----
    int wave = tid >> 6;
    int lane = tid & 63;
    int tok = id * 4 + wave;
    if (tok >= T_TOK) return;

    const float* xr = x + (size_t)tok * DIM;
    double aR[NEXP], aN[NEXP];
#pragma unroll
    for (int e = 0; e < NEXP; ++e) { aR[e] = 0.0; aN[e] = 0.0; }

#pragma unroll 4
    for (int i = 0; i < 16; ++i) {
        int k = lane + i * 64;
        double xv = (double)xr[k];
        const float4* wr4 = (const float4*)(w_route + (size_t)k * 8);
        const float4* wn4 = (const float4*)(w_noise + (size_t)k * 8);
        float4 r0 = wr4[0], r1 = wr4[1];
        float4 n0 = wn4[0], n1 = wn4[1];
        aR[0] += xv * (double)r0.x; aR[1] += xv * (double)r0.y;
        aR[2] += xv * (double)r0.z; aR[3] += xv * (double)r0.w;
        aR[4] += xv * (double)r1.x; aR[5] += xv * (double)r1.y;
        aR[6] += xv * (double)r1.z; aR[7] += xv * (double)r1.w;
        aN[0] += xv * (double)n0.x; aN[1] += xv * (double)n0.y;
        aN[2] += xv * (double)n0.z; aN[3] += xv * (double)n0.w;
        aN[4] += xv * (double)n1.x; aN[5] += xv * (double)n1.y;
        aN[6] += xv * (double)n1.z; aN[7] += xv * (double)n1.w;
    }
#pragma unroll
    for (int e = 0; e < NEXP; ++e) {
        for (int s = 1; s < 64; s <<= 1) {
            aR[e] += __shfl_xor(aR[e], s);
            aN[e] += __shfl_xor(aN[e], s);
        }
    }
    if (lane == 0) {
        double nv[NEXP];
#pragma unroll
        for (int e = 0; e < NEXP; ++e) {
            double lg = aR[e] + (double)b_route[e];
            double nl = aN[e] + (double)b_noise[e];
            double sp = (nl > 30.0) ? nl : log1p(exp(nl));
            nv[e] = lg + (double)noise[(size_t)tok * 8 + e] * sp;
        }
        int i1 = 0;
#pragma unroll
        for (int e = 1; e < NEXP; ++e) if (nv[e] > nv[i1]) i1 = e;
        int i2 = (i1 == 0) ? 1 : 0;
#pragma unroll
        for (int e = 0; e < NEXP; ++e) if (e != i1 && nv[e] > nv[i2]) i2 = e;
        double m = nv[i1];
        double e2 = exp(nv[i2] - m);
        double s = 1.0 + e2;
        gate_tok[2 * tok + 0] = (float)(1.0 / s);
        gate_tok[2 * tok + 1] = (float)(e2 / s);
        int p1 = atomicAdd(&counts[i1], 1);
        lists[i1 * T_TOK + p1] = 2 * tok + 0;
        int p2 = atomicAdd(&counts[i2], 1);
        lists[i2 * T_TOK + p2] = 2 * tok + 1;
    }
}

// ---------------- prefix: bases[e] = exclusive prefix sum of counts ----------------
__global__ void prefix_kernel(const int* __restrict__ counts, int* __restrict__ bases) {
    if (threadIdx.x == 0 && blockIdx.x == 0) {
        int s = 0;
#pragma unroll
        for (int e = 0; e < NEXP; ++e) { bases[e] = s; s += counts[e]; }
    }
}

// ---------------- pack A: flat over the 16384 packed rows ----------------
__global__ __launch_bounds__(256) void pack_a_kernel(
    const float* __restrict__ x, const int* __restrict__ bases,
    const int* __restrict__ lists, bf16_t* __restrict__ Ap, int* __restrict__ inv)
{
    int wave = threadIdx.x >> 6, lane = threadIdx.x & 63;
    int p = blockIdx.x * 4 + wave;
    int e = 0;
#pragma unroll
    for (int i = 1; i < NEXP; ++i) e += (p >= bases[i]);
    int pos = p - bases[e];
    int entry = lists[e * T_TOK + pos];
    if (lane == 0) inv[entry] = p;
    const float4* src = (const float4*)(x + (size_t)(entry >> 1) * DIM);
    bf16x4* dst = (bf16x4*)(Ap + (size_t)p * DIM);
#pragma unroll
    for (int j = 0; j < 4; ++j) {
        float4 v = src[lane + j * 64];
        bf16x4 o;
        o[0] = (bf16_t)v.x; o[1] = (bf16_t)v.y; o[2] = (bf16_t)v.z; o[3] = (bf16_t)v.w;
        dst[lane + j * 64] = o;
    }
}

// ---------------- grouped GEMM: 128x128 tile, BK=64, 4 waves, counted-vmcnt dbuf ----------------
// r14 VERBATIM (239us/GEMM measured): 64KB LDS -> 2 blocks/CU + XCD
// expert-clustering (e = wg&7) + two-barrier loop with counted s_waitcnt
// vmcnt(8) + T2 swizzle + T5 setprio. MODE 1 writes Yp as bf16.
template<int K, int MODE>
__global__ __launch_bounds__(256) void moe_gemm_kernel(
    const bf16_t* __restrict__ Asrc, const bf16_t* __restrict__ Wt,
    const float* __restrict__ bias,
    const int* __restrict__ counts, const int* __restrict__ bases,
    const int* __restrict__ lists, const float* __restrict__ gate_tok,
    bf16_t* __restrict__ Hout, bf16_t* __restrict__ Yp)
{
    constexpr int N = (MODE == 0) ? DFF : DIM;
    constexpr int NT = K / 64;
    constexpr int NY = N / 128;

    int wg = blockIdx.x + 64 * (blockIdx.y + NY * blockIdx.z);
    int e = wg & 7;
    int inner = wg >> 3;
    int xi = inner & 63;
    int yi = inner >> 6;

    int cnt = counts[e];
    int m0 = xi * 128;
    if (m0 >= cnt) return;
    int base = bases[e];
    int n0 = yi * 128;
    const int* list = lists + e * T_TOK;
    const bf16_t* W = Wt + (size_t)e * N * K;

    __shared__ __attribute__((aligned(16))) bf16_t Ah0[128 * 64];
    __shared__ __attribute__((aligned(16))) bf16_t Bh0[128 * 64];
    __shared__ __attribute__((aligned(16))) bf16_t Ah1[128 * 64];
    __shared__ __attribute__((aligned(16))) bf16_t Bh1[128 * 64];

    int tid = threadIdx.x;
    int lane = tid & 63;
    int wave = tid >> 6;
    int wr = wave >> 1, wc = wave & 1;

    int kcs = (((lane & 7) ^ (lane >> 3)) << 3);
    const bf16_t* pA[4];
    const bf16_t* pB[4];
#pragma unroll
    for (int i = 0; i < 4; ++i) {
        int c = wave * 4 + i;
        int r = c * 8 + (lane >> 3);
        int ridx = m0 + r; if (ridx > cnt - 1) ridx = cnt - 1;
        pA[i] = Asrc + (size_t)(base + ridx) * K + kcs;
        pB[i] = W + (size_t)(n0 + r) * K + kcs;
    }

    f32x4 acc[4][4];
#pragma unroll
    for (int m = 0; m < 4; ++m)
#pragma unroll
        for (int n = 0; n < 4; ++n)
            acc[m][n] = (f32x4){0.f, 0.f, 0.f, 0.f};

    int g = lane >> 4, ln15 = lane & 15, ln7 = lane & 7;

#define STAGE(An, Bn, k0) do {                                               \
    _Pragma("unroll") for (int i = 0; i < 4; ++i) {                          \
        int c = wave * 4 + i;                                                \
        gll16(pA[i] + (k0), (An) + c * 512);                                 \
        gll16(pB[i] + (k0), (Bn) + c * 512);                                 \
    } } while (0)

#define COMPUTE(Ab, Bb) do {                                                 \
    _Pragma("unroll") for (int kk = 0; kk < 2; ++kk) {                       \
        bf16x8 a[4], b[4];                                                   \
        int sw = (((kk * 4 + g) ^ ln7) << 3);                                \
        _Pragma("unroll") for (int n = 0; n < 4; ++n)                        \
            b[n] = *(const bf16x8*)((Bb) + (wc * 64 + n * 16 + ln15) * 64 + sw); \
        _Pragma("unroll") for (int m = 0; m < 4; ++m)                        \
            a[m] = *(const bf16x8*)((Ab) + (wr * 64 + m * 16 + ln15) * 64 + sw); \
        __builtin_amdgcn_s_setprio(1);                                       \
        _Pragma("unroll") for (int m = 0; m < 4; ++m)                        \
            _Pragma("unroll") for (int n = 0; n < 4; ++n)                    \
                acc[m][n] = __builtin_amdgcn_mfma_f32_16x16x32_bf16(a[m], b[n], acc[m][n], 0, 0, 0); \
        __builtin_amdgcn_s_setprio(0);                                       \
    } } while (0)

#define FENCE() __builtin_amdgcn_sched_barrier(0)
#define WAITV(n) asm volatile("s_waitcnt vmcnt(" #n ")" ::: "memory")

    STAGE(Ah0, Bh0, 0);

    for (int kt = 0; kt < NT; kt += 2) {
        if (kt + 1 < NT) { STAGE(Ah1, Bh1, (kt + 1) * 64); WAITV(8); }
        else             { WAITV(0); }
        FENCE(); __builtin_amdgcn_s_barrier(); FENCE();
        COMPUTE(Ah0, Bh0);
        FENCE(); __builtin_amdgcn_s_barrier(); FENCE();
        if (kt + 2 < NT) { STAGE(Ah0, Bh0, (kt + 2) * 64); WAITV(8); }
        else             { WAITV(0); }
        FENCE(); __builtin_amdgcn_s_barrier(); FENCE();
        COMPUTE(Ah1, Bh1);
        FENCE(); __builtin_amdgcn_s_barrier(); FENCE();
    }
#undef STAGE
#undef COMPUTE
#undef FENCE
#undef WAITV

    int l4 = lane >> 4;
    float bs[4];
#pragma unroll
    for (int n = 0; n < 4; ++n)
        bs[n] = bias[e * N + n0 + wc * 64 + n * 16 + ln15];
#pragma unroll
    for (int m = 0; m < 4; ++m) {
#pragma unroll
        for (int j = 0; j < 4; ++j) {
            int grow = m0 + wr * 64 + m * 16 + l4 * 4 + j;
            if (grow >= cnt) continue;
            if constexpr (MODE == 0) {
#pragma unroll
                for (int n = 0; n < 4; ++n) {
                    int gcol = n0 + wc * 64 + n * 16 + ln15;
                    float v = acc[m][n][j] + bs[n];
                    Hout[(size_t)(base + grow) * DFF + gcol] = (bf16_t)fmaxf(v, 0.f);
                }
            } else {
                float gt = gate_tok[list[grow]];
#pragma unroll
                for (int n = 0; n < 4; ++n) {
                    int gcol = n0 + wc * 64 + n * 16 + ln15;
                    Yp[(size_t)(base + grow) * DIM + gcol] = (bf16_t)(gt * (acc[m][n][j] + bs[n]));
                }
            }
        }
    }
}

// ---------------- combine: out[t] = Yp[inv[2t]] + Yp[inv[2t+1]] (bf16 Yp), 2 rows/block ----------------
__global__ __launch_bounds__(256) void combine_kernel(
    const bf16_t* __restrict__ Yp, const int* __restrict__ inv,
    float* __restrict__ out)
{
#pragma unroll
    for (int q = 0; q < 2; ++q) {
        int t = blockIdx.x * 2 + q;
        int p0 = inv[2 * t], p1 = inv[2 * t + 1];
        const bf16x4* a = (const bf16x4*)(Yp + (size_t)p0 * DIM);
        const bf16x4* b = (const bf16x4*)(Yp + (size_t)p1 * DIM);
        float4* o = (float4*)(out + (size_t)t * DIM);
        int i = threadIdx.x;
        bf16x4 va = a[i], vb = b[i];
        o[i] = make_float4((float)va[0] + (float)vb[0], (float)va[1] + (float)vb[1],
                           (float)va[2] + (float)vb[2], (float)va[3] + (float)vb[3]);
    }
}

extern "C" void kernel_launch(void* const* d_in, const int* in_sizes, int n_in,
                              void* d_out, int out_size, void* d_ws, size_t ws_size,
                              hipStream_t stream) {
    const float* x       = (const float*)d_in[0];
    const float* noise   = (const float*)d_in[1];
    const float* w_route = (const float*)d_in[2];
    const float* b_route = (const float*)d_in[3];
    const float* w_noise = (const float*)d_in[4];
    const float* b_noise = (const float*)d_in[5];
    const float* w1      = (const float*)d_in[6];
    const float* b1      = (const float*)d_in[7];
    const float* w2      = (const float*)d_in[8];
    const float* b2      = (const float*)d_in[9];
    float* out = (float*)d_out;

    char* ws = (char*)d_ws;
    size_t off = 0;
    auto alloc = [&](size_t bytes) {
        off = (off + 255) & ~(size_t)255;
        size_t r = off; off += bytes; return r;
    };
    int*    counts   = (int*)   (ws + alloc(32));
    int*    bases    = (int*)   (ws + alloc(32));
    int*    lists    = (int*)   (ws + alloc((size_t)NEXP * T_TOK * 4));
    float*  gate_tok = (float*) (ws + alloc((size_t)T_TOK * 2 * 4));
    int*    inv      = (int*)   (ws + alloc((size_t)T_TOK * 2 * 4));
    bf16_t* w1t      = (bf16_t*)(ws + alloc((size_t)NEXP * DFF * DIM * 2));
    bf16_t* w2t      = (bf16_t*)(ws + alloc((size_t)NEXP * DIM * DFF * 2));
    bf16_t* Ap       = (bf16_t*)(ws + alloc((size_t)T_TOK * 2 * DIM * 2));
    bf16_t* H        = (bf16_t*)(ws + alloc((size_t)T_TOK * 2 * DFF * 2));
    bf16_t* Yp       = w1t;   // w1t (64MB) dead after GEMM1; Yp bf16 (32MB)
    (void)ws_size; (void)in_sizes; (void)n_in; (void)out_size;

    hipMemsetAsync(counts, 0, 32, stream);

    // router (blocks 0..2047, runs first) overlaps with both weight transposes.
    fused_pre_kernel<<<18432, 256, 0, stream>>>(x, noise, w_route, b_route, w_noise, b_noise,
                                                w1, w2, w1t, w2t, counts, lists, gate_tok);

    prefix_kernel<<<1, 64, 0, stream>>>(counts, bases);
    pack_a_kernel<<<T_TOK * 2 / 4, 256, 0, stream>>>(x, bases, lists, Ap, inv);

    moe_gemm_kernel<DIM, 0><<<dim3(64, DFF / 128, NEXP), 256, 0, stream>>>(
        Ap, w1t, b1, counts, bases, lists, gate_tok, H, nullptr);
    moe_gemm_kernel<DFF, 1><<<dim3(64, DIM / 128, NEXP), 256, 0, stream>>>(
        H, w2t, b2, counts, bases, lists, gate_tok, nullptr, Yp);

    combine_kernel<<<T_TOK / 2, 256, 0, stream>>>(Yp, inv, out);
}